// Round 6
// baseline (60.619 us; speedup 1.0000x reference)
//
#include <hip/hip_runtime.h>

// Nearest-neighbor scatter-to-grid with per-tile candidate culling.
//
// Structure (round-5, verified absmax 0.0): one block per 16x16-cell tile;
// points farther from the tile center than dmin + 2r + eps can never be any
// cell's argmin (r = tile half-diagonal) -> ~40 survivors of 1024.
// Round-6 micro-opts: float4 phase-1 loads; phase-2 padded to unroll-8
// groups with +inf sentinels (never selected -> semantics unchanged).
//
// Safety: phase-2 d2 uses the verified bit-exact formula; pruning margin
// eps = 8e-3 >> 4x the max argmin displacement from f32 formula rounding.
// Compaction order is scrambled -> explicit (d2 < best) || (d2 == best &&
// n < bi) tie-break == jnp.argmin first-occurrence.
//
// Bit-exactness contract (verified absmax 0.0, rounds 2-5):
//  - pp  = round(px*px) + round(py*py)      (XLA fused mul+reduce, no FMA)
//  - dot = fma(gy, py, round(gx*px))        (Eigen gemm: sequential FMA)
//  - d2  = round(pp - 2*dot)                (2*dot exact; single rounding)

#define GRID_H 256
#define GRID_W 256
#define GRID_G (GRID_H * GRID_W)
#define NPTS   1024
#define BLOCK  256
#define TILE   16
#define TILES_PER_B ((GRID_H / TILE) * (GRID_W / TILE))   // 256

__global__ __launch_bounds__(BLOCK) void nn_tile_kernel(
    const float* __restrict__ R,    // [B, C, N]
    const float* __restrict__ XY,   // [B, 2, N]
    float*       __restrict__ out,  // [B, C, H, W]
    int B, int C, int N)
{
#pragma clang fp contract(off)
    __shared__ float4 cand[NPTS + 8];  // {px, py, pp, as_float(n)} + sentinels
    __shared__ float  wmin[4];
    __shared__ int    lds_cnt;

    const int blk = blockIdx.x;                 // [0, B*256)
    const int b   = blk >> 8;
    const int t   = blk & 255;
    const int tx  = t & 15, ty = t >> 4;        // tile coords

    const int tid  = threadIdx.x;
    const int lane = tid & 63;
    const int wid  = tid >> 6;

    if (tid == 0) lds_cnt = 0;

    // ---- Phase 1: distance-to-tile-center for all N points (4/thread, vec4)
    const float cx = (float)(tx * TILE + 8) * (1.0f / GRID_W);
    const float cy = (float)(ty * TILE + 8) * (1.0f / GRID_H);

    const float* __restrict__ pxp = XY + (size_t)b * 2 * N;  // 16B-aligned
    const float* __restrict__ pyp = pxp + N;                 // +4096B, aligned

    const float4 px4 = ((const float4*)pxp)[tid];   // n = 4*tid + c
    const float4 py4 = ((const float4*)pyp)[tid];
    const float px[4] = {px4.x, px4.y, px4.z, px4.w};
    const float py[4] = {py4.x, py4.y, py4.z, py4.w};

    float dc2[4];
    float local_min = 3.4e38f;
    #pragma unroll
    for (int c = 0; c < 4; ++c) {
        float dx = px[c] - cx;
        float dy = py[c] - cy;
        dc2[c] = dx * dx + dy * dy;
        local_min = fminf(local_min, dc2[c]);
    }
    // block-wide min of center distances
    #pragma unroll
    for (int off = 32; off >= 1; off >>= 1)
        local_min = fminf(local_min, __shfl_xor(local_min, off));
    if (lane == 0) wmin[wid] = local_min;
    __syncthreads();
    const float m2 = fminf(fminf(wmin[0], wmin[1]), fminf(wmin[2], wmin[3]));
    const float dmin = sqrtf(m2);
    // keep p iff dist(center,p) <= dmin + 2r + eps ; r = sqrt(2)*7.5/256
    const float dthr  = dmin + 0.0828638f + 0.008f;
    const float dthr2 = dthr * dthr;

    // ---- Compaction: ballot + wave-base atomic (order scrambled; phase 2
    //      tie-break restores first-occurrence semantics)
    #pragma unroll
    for (int c = 0; c < 4; ++c) {
        const int n = 4 * tid + c;
        const bool keep = (dc2[c] <= dthr2);
        unsigned long long mask = __ballot(keep);
        int prefix = __popcll(mask & ((1ull << lane) - 1ull));
        int wcnt   = __popcll(mask);
        int base = 0;
        if (lane == 0) base = atomicAdd(&lds_cnt, wcnt);
        base = __shfl(base, 0);
        if (keep) {
            float pp = px[c] * px[c] + py[c] * py[c];  // contract off: ref rounding
            cand[base + prefix] = make_float4(px[c], py[c], pp, __int_as_float(n));
        }
    }
    __syncthreads();
    const int K = lds_cnt;    // >= 1 (the center-min point always survives)

    // Sentinels: d2 evaluates to +inf, n = INT_MAX -> never selected.
    if (tid < 8)
        cand[K + tid] = make_float4(0.0f, 0.0f, __builtin_huge_valf(),
                                    __int_as_float(0x7fffffff));
    __syncthreads();
    const int Kpad = (K + 7) & ~7;

    // ---- Phase 2: per-cell argmin over K candidates, unroll-8 groups
    const int x = tx * TILE + (tid & 15);
    const int y = ty * TILE + (tid >> 4);
    const float gx = ((float)x + 0.5f) * (1.0f / GRID_W);
    const float gy = ((float)y + 0.5f) * (1.0f / GRID_H);

    float best = 3.4e38f;
    int   bi   = 0x7fffffff;
    for (int k = 0; k < Kpad; k += 8) {
        #pragma unroll
        for (int u = 0; u < 8; ++u) {
            float4 q = cand[k + u];               // wave-uniform -> broadcast
            int    n = __float_as_int(q.w);
            float  dot = fmaf(gy, q.y, gx * q.x); // Eigen gemm rounding
            float  d2  = fmaf(-2.0f, dot, q.z);   // exact 2*dot, single rounding
            bool better = (d2 < best) || (d2 == best && n < bi);
            best = better ? d2 : best;
            bi   = better ? n  : bi;
        }
    }

    const int g = y * GRID_W + x;
    const float* rb = R + (size_t)b * C * N;
    float*       ob = out + (size_t)b * C * GRID_G;
    #pragma unroll
    for (int c = 0; c < 4; ++c) {
        ob[(size_t)c * GRID_G + g] = rb[(size_t)c * N + bi];
    }
}

extern "C" void kernel_launch(void* const* d_in, const int* in_sizes, int n_in,
                              void* d_out, int out_size, void* d_ws, size_t ws_size,
                              hipStream_t stream) {
    const float* R  = (const float*)d_in[0];   // [B, C, N] f32
    const float* XY = (const float*)d_in[1];   // [B, 2, N] f32
    float* out = (float*)d_out;                // [B, C, H, W] f32

    const int N = NPTS;
    const int B = in_sizes[1] / (2 * N);       // 2
    const int C = in_sizes[0] / (B * N);       // 4

    const int nblocks = B * TILES_PER_B;       // 512
    nn_tile_kernel<<<nblocks, BLOCK, 0, stream>>>(R, XY, out, B, C, N);
}